// Round 4
// baseline (524.945 us; speedup 1.0000x reference)
//
#include <hip/hip_runtime.h>

#define TT 512
#define II 10
#define HH 32

typedef float v2f __attribute__((ext_vector_type(2)));

__device__ __forceinline__ float frcp(float v) { return __builtin_amdgcn_rcpf(v); }
__device__ __forceinline__ float sigm(float v) { return frcp(1.0f + __expf(-v)); }
__device__ __forceinline__ float tanh_f(float v) { return 1.0f - 2.0f * frcp(__expf(2.0f * v) + 1.0f); }

// Layout: wave = 1 batch row. lane = (unit j = lane&31, k-half kh = lane>>5).
// Each thread computes ALL 4 gates for unit j over its k-half: 8 k-PAIRED
// float2 W_hh weights/gate + 3 k-paired W_ih pairs/gate (bias folded in as a
// virtual input {1,.}x{bias,0} on kh=1). pk_fma consumes h as natural adjacent
// pairs from ds_read_b128 -> ZERO splat movs. Demand ~119 VGPRs: fits the
// 128-arch tier that waves_per_eu(2,2) reliably grants (R3 evidence: allocator
// gives arch = half the unified budget; 205-float demand at 128 arch caused
// ~154 cyc/step of v_accvgpr_read tax -- this layout eliminates it).
// agpr=0 => 4 waves/SIMD resident for latency hiding. Grid 1024 = 4 blocks/CU.
// Each wave owns its row's h slots in LDS -> no __syncthreads anywhere.
extern "C" __global__ __launch_bounds__(256)
__attribute__((amdgpu_waves_per_eu(2, 2)))
#if __has_attribute(amdgpu_num_vgpr)
__attribute__((amdgpu_num_vgpr(128)))
#endif
void lstm_fused(const float* __restrict__ x,
                const float* __restrict__ h0,
                const float* __restrict__ c0,
                const float* __restrict__ W_ih,
                const float* __restrict__ W_hh,
                const float* __restrict__ b_ih,
                const float* __restrict__ b_hh,
                const float* __restrict__ W_lin,
                const float* __restrict__ b_lin,
                float* __restrict__ out)
{
    __shared__ __align__(16) float h_lds[4][HH];

    const int tid  = threadIdx.x;
    const int wv   = tid >> 6;
    const int lane = tid & 63;
    const int kh   = lane >> 5;      // k-half this thread sums
    const int j    = lane & 31;      // hidden unit owned by this thread
    const bool khb = (kh != 0);
    const int b    = blockIdx.x * 4 + wv;

    // ---- weights into registers, k-paired ----
    v2f w[4][8];     // W_hh[row][kh*16 + 2q .. +2q+1]
    v2f wi[4][3];    // x-projection pairs (+ bias-as-input on kh=1)
    #pragma unroll
    for (int g = 0; g < 4; ++g) {
        const int row = g * HH + j;
        const float4* wr = reinterpret_cast<const float4*>(W_hh + row * HH + kh * 16);
        #pragma unroll
        for (int q = 0; q < 4; ++q) {
            const float4 v = wr[q];
            w[g][2 * q + 0] = v2f{v.x, v.y};
            w[g][2 * q + 1] = v2f{v.z, v.w};
        }
        const float* qi = W_ih + row * II;
        if (!khb) {
            wi[g][0] = v2f{qi[0], qi[1]};
            wi[g][1] = v2f{qi[2], qi[3]};
            wi[g][2] = v2f{qi[4], qi[5]};
        } else {
            wi[g][0] = v2f{qi[6], qi[7]};
            wi[g][1] = v2f{qi[8], qi[9]};
            wi[g][2] = v2f{b_ih[row] + b_hh[row], 0.0f};  // virtual input {1,.}
        }
    }

    float c = c0[b * HH + j];        // identical on both halves
    h_lds[wv][j] = h0[b * HH + j];   // lanes j and j+32: same addr, same value
    float hv = 0.0f;

    // x addressing: row base is wave-uniform; kh selects 6-float sub-offset.
    // Pairs per step: kh0: {x0,x1},{x2,x3},{x4,x5}; kh1: {x6,x7},{x8,x9},dup
    // (dup's .x replaced by 1.0 -> bias virtual input; .y multiplied by 0).
    const float* xrow = x + (size_t)b * (TT * II);
    const int koff  = kh * 6;
    const int k2off = khb ? 2 : 4;   // third pair's extra float offset

    v2f xa0, xa1, xa2, xb0, xb1, xb2;
    {
        const float2* p = reinterpret_cast<const float2*>(xrow + koff);
        float2 e0 = p[0], e1 = p[1];
        float2 e2 = *reinterpret_cast<const float2*>(xrow + koff + k2off);
        xa0 = v2f{e0.x, e0.y}; xa1 = v2f{e1.x, e1.y};
        xa2 = v2f{khb ? 1.0f : e2.x, e2.y};
    }

    #define PREFETCH(B0, B1, B2, tnext)                                       \
        {                                                                     \
            const int tn_ = (tnext) < TT ? (tnext) : (TT - 1);                \
            const float* base_ = xrow + tn_ * II + koff;                      \
            const float2* p_ = reinterpret_cast<const float2*>(base_);        \
            float2 e0_ = p_[0], e1_ = p_[1];                                  \
            float2 e2_ = *reinterpret_cast<const float2*>(base_ + k2off);     \
            B0 = v2f{e0_.x, e0_.y}; B1 = v2f{e1_.x, e1_.y};                   \
            B2 = v2f{khb ? 1.0f : e2_.x, e2_.y};                              \
        }

    #define STEP(X0, X1, X2)                                                  \
        {                                                                     \
            v2f a0 = wi[0][0] * (X0);                                         \
            v2f a1 = wi[1][0] * (X0);                                         \
            v2f a2 = wi[2][0] * (X0);                                         \
            v2f a3 = wi[3][0] * (X0);                                         \
            a0 = __builtin_elementwise_fma(wi[0][1], (X1), a0);               \
            a1 = __builtin_elementwise_fma(wi[1][1], (X1), a1);               \
            a2 = __builtin_elementwise_fma(wi[2][1], (X1), a2);               \
            a3 = __builtin_elementwise_fma(wi[3][1], (X1), a3);               \
            a0 = __builtin_elementwise_fma(wi[0][2], (X2), a0);               \
            a1 = __builtin_elementwise_fma(wi[1][2], (X2), a1);               \
            a2 = __builtin_elementwise_fma(wi[2][2], (X2), a2);               \
            a3 = __builtin_elementwise_fma(wi[3][2], (X2), a3);               \
            _Pragma("unroll")                                                 \
            for (int q = 0; q < 4; ++q) {                                     \
                const float4 h4 = *reinterpret_cast<const float4*>(           \
                    &h_lds[wv][kh * 16 + 4 * q]);                             \
                const v2f hp0 = v2f{h4.x, h4.y};                              \
                const v2f hp1 = v2f{h4.z, h4.w};                              \
                a0 = __builtin_elementwise_fma(w[0][2 * q],     hp0, a0);     \
                a1 = __builtin_elementwise_fma(w[1][2 * q],     hp0, a1);     \
                a2 = __builtin_elementwise_fma(w[2][2 * q],     hp0, a2);     \
                a3 = __builtin_elementwise_fma(w[3][2 * q],     hp0, a3);     \
                a0 = __builtin_elementwise_fma(w[0][2 * q + 1], hp1, a0);     \
                a1 = __builtin_elementwise_fma(w[1][2 * q + 1], hp1, a1);     \
                a2 = __builtin_elementwise_fma(w[2][2 * q + 1], hp1, a2);     \
                a3 = __builtin_elementwise_fma(w[3][2 * q + 1], hp1, a3);     \
            }                                                                 \
            float s0 = a0.x + a0.y;                                           \
            float s1 = a1.x + a1.y;                                           \
            float s2 = a2.x + a2.y;                                           \
            float s3 = a3.x + a3.y;                                           \
            s0 += __shfl_xor(s0, 32);                                         \
            s1 += __shfl_xor(s1, 32);                                         \
            s2 += __shfl_xor(s2, 32);                                         \
            s3 += __shfl_xor(s3, 32);                                         \
            const float ig = sigm(s0);                                        \
            const float fg = sigm(s1);                                        \
            const float gg = tanh_f(s2);                                      \
            const float og = sigm(s3);                                        \
            c  = fg * c + ig * gg;                                            \
            hv = og * tanh_f(c);                                              \
            h_lds[wv][j] = hv;                                                \
        }

    for (int t = 0; t < TT; t += 2) {
        PREFETCH(xb0, xb1, xb2, t + 1);
        STEP(xa0, xa1, xa2);
        PREFETCH(xa0, xa1, xa2, t + 2);
        STEP(xb0, xb1, xb2);
    }
    #undef STEP
    #undef PREFETCH

    // out[b] = dot(hT, W_lin) + b_lin -- butterfly within each 32-lane half
    float p = hv * W_lin[j];
    p += __shfl_xor(p, 1);
    p += __shfl_xor(p, 2);
    p += __shfl_xor(p, 4);
    p += __shfl_xor(p, 8);
    p += __shfl_xor(p, 16);
    if (lane == 0) out[b] = p + b_lin[0];
}

extern "C" void kernel_launch(void* const* d_in, const int* in_sizes, int n_in,
                              void* d_out, int out_size, void* d_ws, size_t ws_size,
                              hipStream_t stream) {
    const float* x     = (const float*)d_in[0];
    const float* h0    = (const float*)d_in[1];
    const float* c0    = (const float*)d_in[2];
    const float* W_ih  = (const float*)d_in[3];
    const float* W_hh  = (const float*)d_in[4];
    const float* b_ih  = (const float*)d_in[5];
    const float* b_hh  = (const float*)d_in[6];
    const float* W_lin = (const float*)d_in[7];
    const float* b_lin = (const float*)d_in[8];
    float* out = (float*)d_out;

    const int B = in_sizes[1] / HH;   // 4096
    dim3 grid(B / 4), block(256);
    lstm_fused<<<grid, block, 0, stream>>>(x, h0, c0, W_ih, W_hh, b_ih, b_hh, W_lin, b_lin, out);
}